// Round 2
// baseline (482.316 us; speedup 1.0000x reference)
//
#include <hip/hip_runtime.h>

// ---------------------------------------------------------------------------
// SelfInteraction: 2 layers, N=16384, C=128, fp32 I/O.
// fp16 hi/lo split-precision MFMA GEMMs (K''=3K segments: AhBh, AhBl, AlBh).
// Round 2: 64x128 tiles (2x block count), GEMM3+GEMMv merged into one
// dispatch, e2 gating fused into GEMM2 epilogue (G matrix eliminated),
// eq-layernorm writes next layer's sc' operand directly (e1 runs once).
// ---------------------------------------------------------------------------

typedef _Float16 half8 __attribute__((ext_vector_type(8)));
typedef float floatx4 __attribute__((ext_vector_type(4)));

static inline int cdiv_h(int a, int b){ return (a + b - 1) / b; }

// ---------------------------- device helpers -------------------------------

__device__ __forceinline__ void stage16(const char* gaddr, char* lds_wave_base){
#if __has_builtin(__builtin_amdgcn_global_load_lds)
  // dest = wave-uniform base + lane*16 (measured semantics, learn_hip m104/m108)
  __builtin_amdgcn_global_load_lds((const __attribute__((address_space(1))) unsigned int*)gaddr,
                                   (__attribute__((address_space(3))) unsigned int*)lds_wave_base,
                                   16, 0, 0);
#endif
}

__device__ __forceinline__ float wave_sum64(float x){
  #pragma unroll
  for (int m = 32; m; m >>= 1) x += __shfl_xor(x, m, 64);
  return x;
}

__device__ __forceinline__ void split_store(_Float16* p0, _Float16* p1, float v){
  _Float16 hi = (_Float16)v;
  *p0 = hi;
  *p1 = (_Float16)(v - (float)hi);
}

// ---------------------------- weight prep (all 8 tensors, 1 dispatch) ------
// writes BT' [col][3K]: seg0=hi, seg1=lo, seg2=hi (dup), scale folded in.
__global__ __launch_bounds__(256) void prep_all(const float* __restrict__ w1,
                                                const float* __restrict__ w2,
                                                const float* __restrict__ w0,
                                                const float* __restrict__ wv,
                                                _Float16* __restrict__ W){
  int idx = blockIdx.x*256 + threadIdx.x;
  const int P = 475136;
  if (idx >= 2*P) return;
  int l = (idx >= P) ? 1 : 0;
  int t = idx - l*P;
  const float RS384 = 0.051031036307982884f;   // 1/sqrt(384)
  _Float16* base = W + (size_t)l*1425408;
  const float* w; int K, ldw, col, k; float scale; _Float16* o;
  if (t < 147456){ int c = t/384; k = t - c*384;
    w = w1 + (size_t)l*147456; K = 384; ldw = 384; col = c; scale = RS384; o = base; }
  else if (t < 393216){ int u = t - 147456; int c = u/384; k = u - c*384;
    w = w2 + (size_t)l*294912; K = 384; ldw = 768; col = c; scale = RS384; o = base + 442368; }
  else if (t < 442368){ int u = t - 393216; int c = u/384; k = u - c*384;
    w = w0 + (size_t)l*49152; K = 384; ldw = 128; col = c; scale = RS384; o = base + 1179648; }
  else { int u = t - 442368; int c = u/256; k = u - c*256;
    w = wv + (size_t)l*32768; K = 256; ldw = 128; col = c; scale = 0.0625f; o = base + 1327104; }
  float v = w[(size_t)k*ldw + col] * scale;
  _Float16 hi = (_Float16)v;
  size_t b = (size_t)col*3*K + k;
  o[b]       = hi;
  o[b + K]   = (_Float16)(v - (float)hi);
  o[b + 2*K] = hi;
}

// ---------------------------- E0: unpack x ---------------------------------
__global__ __launch_bounds__(256) void e0_load(const float* __restrict__ x,
                                               float* __restrict__ S, float* __restrict__ V,
                                               int R, int row0){
  int idx = blockIdx.x*256 + threadIdx.x;
  if (idx >= R*512) return;
  int n = idx >> 9, j = idx & 511;
  float val = x[(size_t)(row0 + n)*512 + j];
  if (j < 128) S[(size_t)n*128 + j] = val;
  else {
    int jj = j - 128;
    int ch = jj / 3;
    int d  = jj - ch*3;
    V[((size_t)n*3 + d)*128 + ch] = val;
  }
}

// ---------------------------- E1: build sc' (layer 0 only) -----------------
__global__ __launch_bounds__(256) void e1_sc(const float* __restrict__ S,
                                             const float* __restrict__ V,
                                             _Float16* __restrict__ A1, int R){
  int idx = blockIdx.x*256 + threadIdx.x;
  if (idx >= R*384) return;
  int n = idx / 384, c = idx - n*384;
  float val;
  if (c < 128) val = S[(size_t)n*128 + c];
  else if (c < 256){ float s = S[(size_t)n*128 + c - 128]; val = s*s; }
  else {
    int ch = c - 256;
    float a = V[((size_t)n*3 + 0)*128 + ch];
    float b = V[((size_t)n*3 + 1)*128 + ch];
    float d = V[((size_t)n*3 + 2)*128 + ch];
    val = (a*a + b*b + d*d) * 0.5773502691896258f;  // 1/sqrt(3)
  }
  split_store(A1 + (size_t)n*768 + c, A1 + (size_t)n*768 + 384 + c, val);
}

// ---------------------------- E3: residual + LN / final --------------------
// one wave per row. doln=1: eq_layernorm back into S,V AND write next
// layer's sc' (A1). doln=0: write final output (s | v interleaved (C,3)).
__global__ __launch_bounds__(256) void e3_fin(float* __restrict__ S, float* __restrict__ V,
                                              const float* __restrict__ OS, const float* __restrict__ OV,
                                              const float* __restrict__ g0, const float* __restrict__ g1,
                                              _Float16* __restrict__ A1,
                                              float* __restrict__ out, int R, int row0, int doln){
  int n = blockIdx.x*4 + (threadIdx.x >> 6);
  int lane = threadIdx.x & 63;
  size_t sb = (size_t)n*128;
  size_t vb = (size_t)n*384;
  float s0 = S[sb + lane]      + OS[sb + lane];
  float s1 = S[sb + 64 + lane] + OS[sb + 64 + lane];
  float v[6];
  #pragma unroll
  for (int k = 0; k < 6; ++k) v[k] = V[vb + k*64 + lane] + OV[vb + k*64 + lane];

  if (doln){
    float mu = wave_sum64(s0 + s1) * (1.0f/128.0f);
    float d0 = s0 - mu, d1 = s1 - mu;
    float var = wave_sum64(d0*d0 + d1*d1) * (1.0f/128.0f);
    float sd = sqrtf(var + 1e-6f);
    float vv = 0.f;
    #pragma unroll
    for (int k = 0; k < 6; ++k) vv += v[k]*v[k];
    float rms = sqrtf(wave_sum64(vv) * (1.0f/384.0f) + 1e-6f);
    float ns0 = d0 / sd * g0[lane];
    float ns1 = d1 / sd * g0[64 + lane];
    S[sb + lane]      = ns0;
    S[sb + 64 + lane] = ns1;
    float nv[6];
    #pragma unroll
    for (int k = 0; k < 6; ++k){
      int j = k*64 + lane;
      nv[k] = v[k] / rms * g1[j & 127];
      V[vb + j] = nv[k];
    }
    // write next layer's sc' operand: [s, s^2, |v|^2/sqrt(3)] split hi/lo
    _Float16* a = A1 + (size_t)n*768;
    split_store(a + lane,        a + 384 + lane,        ns0);
    split_store(a + 64 + lane,   a + 448 + lane,        ns1);
    split_store(a + 128 + lane,  a + 512 + lane,        ns0*ns0);
    split_store(a + 192 + lane,  a + 576 + lane,        ns1*ns1);
    float vva = (nv[0]*nv[0] + nv[2]*nv[2] + nv[4]*nv[4]) * 0.5773502691896258f;
    float vvb = (nv[1]*nv[1] + nv[3]*nv[3] + nv[5]*nv[5]) * 0.5773502691896258f;
    split_store(a + 256 + lane,  a + 640 + lane,        vva);
    split_store(a + 320 + lane,  a + 704 + lane,        vvb);
  } else {
    size_t ob = (size_t)(row0 + n)*512;
    out[ob + lane]      = s0;
    out[ob + 64 + lane] = s1;
    #pragma unroll
    for (int k = 0; k < 6; ++k){
      int j = k*64 + lane;
      int d = j >> 7, ch = j & 127;
      out[ob + 128 + ch*3 + d] = v[k];
    }
  }
}

// ---------------------------- split-GEMM (64x128 tile) ---------------------
// C[M x ncols] = A[M x 2*kbase (hi|lo)] x BT[ncols x 3*kbase]^T
// 64x128 tile, 4 waves as 2(m)x2(n), each wave 32x64 = 2x4 MFMA tiles.
// MODE 0: plain f32 store.        MODE 1: silu + hi/lo split -> SP (h').
// MODE 2: gating epilogue (reads S,V,A1; writes gated A1 / A4 in place).
// MODE 3: dual dispatch — blocks [0,nblk1) = set1 (A,BT,C), rest = set2.
template<int MODE>
__global__ __launch_bounds__(256) void gemm_v2(const _Float16* __restrict__ A,
                                               const _Float16* __restrict__ BT,
                                               float* __restrict__ C,
                                               _Float16* __restrict__ SP,
                                               const float* __restrict__ S,
                                               const float* __restrict__ V,
                                               _Float16* __restrict__ A1g,
                                               _Float16* __restrict__ A4g,
                                               int lda, int kbase, int ldc, int nblk1,
                                               const _Float16* __restrict__ A2_,
                                               const _Float16* __restrict__ BT2_,
                                               float* __restrict__ C2_,
                                               int lda2, int kbase2){
  __shared__ alignas(16) _Float16 lA[2][2048];   // 64 rows x 32 halves
  __shared__ alignas(16) _Float16 lB[2][4096];   // 128 cols x 32 halves
  int bx = blockIdx.x;
  if (MODE == 3 && bx >= nblk1){
    A = A2_; BT = BT2_; C = C2_; lda = lda2; kbase = kbase2; bx -= nblk1;
  }
  const int nsc  = kbase >> 5;
  const int nch  = 3*nsc;
  const int ldbt = 3*kbase;
  const int tid  = threadIdx.x;
  const int wave = tid >> 6, lane = tid & 63;
  const int m0 = bx << 6, c0 = blockIdx.y << 7;
  const int wm = wave & 1, wn = wave >> 1;
  const int r = lane & 15, kg = lane >> 4;

  floatx4 acc[2][4];
  #pragma unroll
  for (int i = 0; i < 2; ++i)
    #pragma unroll
    for (int j = 0; j < 4; ++j) acc[i][j] = (floatx4){0.f, 0.f, 0.f, 0.f};

  auto stage = [&](int c, int buf){
    const int ka = ((c < nsc) ? c : c - nsc) << 5;   // A seg map: hi,hi,lo
    const int kb = c << 5;
    {
      const int lbase = wave*1024;                   // A: wave stages rows [w*16, w*16+16)
      const int off = lbase + lane*16;
      const int row = off >> 6, bir = off & 63;
      const char* ga = (const char*)A + (((size_t)(m0 + row))*lda + ka)*2 + bir;
      stage16(ga, (char*)(&lA[buf][0]) + lbase);
    }
    #pragma unroll
    for (int p = 0; p < 2; ++p){                     // B: wave stages 2KB
      const int lbase = wave*2048 + p*1024;
      const int off = lbase + lane*16;
      const int row = off >> 6, bir = off & 63;
      const char* gb = (const char*)BT + (((size_t)(c0 + row))*ldbt + kb)*2 + bir;
      stage16(gb, (char*)(&lB[buf][0]) + lbase);
    }
  };

  stage(0, 0);
  for (int c = 0; c < nch; ++c){
    __syncthreads();
    if (c + 1 < nch) stage(c + 1, (c + 1) & 1);
    const _Float16* a_ = &lA[c & 1][0];
    const _Float16* b_ = &lB[c & 1][0];
    half8 af[2], bf[4];
    #pragma unroll
    for (int mt = 0; mt < 2; ++mt)
      af[mt] = *(const half8*)(a_ + ((wm*32 + mt*16 + r)*32 + kg*8));
    #pragma unroll
    for (int nt = 0; nt < 4; ++nt)
      bf[nt] = *(const half8*)(b_ + ((wn*64 + nt*16 + r)*32 + kg*8));
    #pragma unroll
    for (int mt = 0; mt < 2; ++mt)
      #pragma unroll
      for (int nt = 0; nt < 4; ++nt)
        acc[mt][nt] = __builtin_amdgcn_mfma_f32_16x16x32_f16(af[mt], bf[nt], acc[mt][nt], 0, 0, 0);
  }

  #pragma unroll
  for (int mt = 0; mt < 2; ++mt){
    #pragma unroll
    for (int nt = 0; nt < 4; ++nt){
      #pragma unroll
      for (int i = 0; i < 4; ++i){
        const int row = m0 + wm*32 + mt*16 + kg*4 + i;   // C/D: row = quad*4+i
        const int col = wn*64 + nt*16 + r;               //      col = lane&15
        float g = acc[mt][nt][i];
        if (MODE == 0 || MODE == 3){
          C[(size_t)row*ldc + c0 + col] = g;
        } else if (MODE == 1){
          float h = g / (1.0f + __expf(-g));             // silu
          split_store(SP + (size_t)row*768 + c0 + col,
                      SP + (size_t)row*768 + 384 + c0 + col, h);
        } else {                                         // MODE 2: gating
          const int gcol = c0 + col;
          if (gcol < 384){
            _Float16* a = A1g + (size_t)row*768;
            float sc = (float)a[gcol] + (float)a[384 + gcol];
            split_store(a + gcol, a + 384 + gcol, sc * g);
          } else {
            const int mm = gcol - 384;                   // 0..255
            const int ch = mm & 127;
            float smul = (mm >= 128) ? 1.4142135623730951f * S[(size_t)row*128 + ch] : 1.0f;
            #pragma unroll
            for (int d = 0; d < 3; ++d){
              float val = V[((size_t)row*3 + d)*128 + ch] * smul * g;
              _Float16* a4 = A4g + ((size_t)row*3 + d)*512;
              split_store(a4 + mm, a4 + 256 + mm, val);
            }
          }
        }
      }
    }
  }
}

// ---------------------------- host launcher --------------------------------

extern "C" void kernel_launch(void* const* d_in, const int* in_sizes, int n_in,
                              void* d_out, int out_size, void* d_ws, size_t ws_size,
                              hipStream_t stream){
  const float* x  = (const float*)d_in[0];
  const float* w1 = (const float*)d_in[1];
  const float* w2 = (const float*)d_in[2];
  const float* w0 = (const float*)d_in[3];
  const float* wv = (const float*)d_in[4];
  const float* g0 = (const float*)d_in[5];
  const float* g1 = (const float*)d_in[6];
  float* out = (float*)d_out;
  const int N = in_sizes[0] / 512;                 // 16384

  const size_t HL = 1425408;                       // halves per layer
  _Float16* W = (_Float16*)d_ws;
  const size_t wbytes = 2*HL*2;                    // 5,701,632 B

  // activations: 10240 B/row (S 512, V 1536, A1 1536, A2 1536, A4 3072,
  // OS 512, OV 1536)
  int cnum = 128;
  for (int cc = 1; cc <= 128; cc <<= 1){
    size_t need = wbytes + (size_t)(N/cc)*10240;
    if (need <= ws_size){ cnum = cc; break; }
  }
  const int R = N / cnum;                          // multiple of 128

  char* p = (char*)d_ws + wbytes;
  float*    Sst = (float*)p;     p += (size_t)R*512;
  float*    Vst = (float*)p;     p += (size_t)R*1536;
  _Float16* A1  = (_Float16*)p;  p += (size_t)R*1536;   // sc' (gated in place)
  _Float16* A2  = (_Float16*)p;  p += (size_t)R*1536;   // h'
  _Float16* A4  = (_Float16*)p;  p += (size_t)R*3072;   // gated vec' (3R x 512)
  float*    OS  = (float*)p;     p += (size_t)R*512;
  float*    OV  = (float*)p;     p += (size_t)R*1536;

  prep_all<<<cdiv_h(950272,256),256,0,stream>>>(w1, w2, w0, wv, W);

  for (int chk = 0; chk < cnum; ++chk){
    const int row0 = chk*R;
    e0_load<<<cdiv_h(R*512,256),256,0,stream>>>(x, Sst, Vst, R, row0);
    e1_sc<<<cdiv_h(R*384,256),256,0,stream>>>(Sst, Vst, A1, R);
    for (int l = 0; l < 2; ++l){
      _Float16* W1p = W + (size_t)l*HL;
      _Float16* W2p = W1p + 442368;
      _Float16* W0p = W1p + 1179648;
      _Float16* WVp = W1p + 1327104;
      // GEMM1: h' = silu(sc' @ w1')
      gemm_v2<1><<<dim3(R/64,3),256,0,stream>>>(A1, W1p, nullptr, A2,
          nullptr, nullptr, nullptr, nullptr, 768, 384, 0, 0,
          nullptr, nullptr, nullptr, 0, 0);
      // GEMM2 + fused gating: g = h' @ w2'; A1 <- sc*g_s; A4 <- vec*g_v
      gemm_v2<2><<<dim3(R/64,5),256,0,stream>>>(A2, W2p, nullptr, nullptr,
          Sst, Vst, A1, A4, 768, 384, 0, 0,
          nullptr, nullptr, nullptr, 0, 0);
      // GEMM3 (OS = gated sc' @ w0') + GEMMv (OV = gated vec' @ wv') merged
      gemm_v2<3><<<dim3(R/16,1),256,0,stream>>>(A1, W0p, OS, nullptr,
          nullptr, nullptr, nullptr, nullptr, 768, 384, 128, R/64,
          A4, WVp, OV, 512, 256);
      // residual + (LN + next sc') or final output
      e3_fin<<<R/4,256,0,stream>>>(Sst, Vst, OS, OV, g0, g1, A1, out,
          R, row0, (l == 0) ? 1 : 0);
    }
  }
}